// Round 5
// baseline (143.045 us; speedup 1.0000x reference)
//
#include <hip/hip_runtime.h>

// Problem constants: B=8, T=12 (BT=96), N=10000, D=16, E=160000
#define NN  10000
#define NE  160000
#define NBT 96
#define DD  16

#define SCAN_THREADS 1024
#define SCHUNK 10                 // ceil(NN / SCAN_THREADS)

#define NODES_PER_BLOCK 64
#define NCHUNK 157                // ceil(NN / NODES_PER_BLOCK)
#define NXCD 8
#define BTD_MAX 6                 // each thread handles bt and bt+48

#define NEP (NE + 3 * NN)         // padded edge capacity (pad-to-4 worst case)

// ---------------- CSR build ----------------

__global__ void k_hist(const int* __restrict__ dst, int* __restrict__ counts) {
    int e = blockIdx.x * blockDim.x + threadIdx.x;
    if (e < NE) atomicAdd(&counts[dst[e]], 1);
}

// Exclusive scan over padded degrees; also writes NaN sentinels into the pad
// region of each row (fmaxf(acc, NaN*v) == acc under IEEE v_max_f32 semantics).
__global__ __launch_bounds__(SCAN_THREADS) void k_scan(const int* __restrict__ counts,
                                                       int* __restrict__ offsets,
                                                       int* __restrict__ cursor,
                                                       int* __restrict__ esrc,
                                                       float* __restrict__ ew,
                                                       int pad) {
    __shared__ int part[SCAN_THREADS];
    int tid = threadIdx.x;
    int begin = tid * SCHUNK;
    int end   = min(begin + SCHUNK, NN);
    int pm = pad - 1;
    int s = 0;
    for (int i = begin; i < end; ++i) s += (counts[i] + pm) & ~pm;
    part[tid] = s;
    __syncthreads();
    for (int off = 1; off < SCAN_THREADS; off <<= 1) {
        int v = (tid >= off) ? part[tid - off] : 0;
        __syncthreads();
        part[tid] += v;
        __syncthreads();
    }
    int run = (tid == 0) ? 0 : part[tid - 1];
    const float qnan = __int_as_float(0x7FC00000);
    for (int i = begin; i < end; ++i) {
        int deg  = counts[i];
        int pdeg = (deg + pm) & ~pm;
        offsets[i] = run;
        cursor[i]  = run;
        for (int p = run + deg; p < run + pdeg; ++p) { esrc[p] = 0; ew[p] = qnan; }
        run += pdeg;
    }
    if (tid == SCAN_THREADS - 1) offsets[NN] = run;
}

__global__ void k_scatter(const int* __restrict__ src, const int* __restrict__ dst,
                          const float* __restrict__ w,
                          int* __restrict__ cursor,
                          int* __restrict__ esrc, float* __restrict__ ew) {
    int e = blockIdx.x * blockDim.x + threadIdx.x;
    if (e >= NE) return;
    int d = dst[e];
    int pos = atomicAdd(&cursor[d], 1);
    esrc[pos] = src[e];
    ew[pos]   = w[e];
}

// ---------------- main gather-max ----------------
// One block = (bt pair {bt0, bt0+48}, 64-node chunk). 256 threads = 64 nodes x 4 d4.
// XCD pinning: idx%8 = XCD; each XCD owns bt0 in {r, r+8, ..., r+40} plus the
// paired slice +48, walking all chunks of one pair before the next -> 1.28 MB
// of V resident in that XCD's 4 MB L2.
template <bool PADDED>
__global__ __launch_bounds__(256) void k_main(const float* __restrict__ V,
                                              const int* __restrict__ offsets,
                                              const int* __restrict__ esrc,
                                              const float* __restrict__ ew,
                                              float* __restrict__ out) {
    int idx = blockIdx.x;
    int r   = idx & 7;
    int k   = idx >> 3;
    int btd = k / NCHUNK;             // 0..5
    int chunk = k - btd * NCHUNK;     // 0..156
    int bt0 = r + 8 * btd;            // 0..47
    int bt1 = bt0 + 48;               // 48..95

    int tid = threadIdx.x;
    int n   = chunk * NODES_PER_BLOCK + (tid >> 2);
    int d4  = (tid & 3) << 2;
    if (n >= NN) return;              // no LDS/sync below: early-exit safe

    const float* __restrict__ Va = V + (size_t)bt0 * (NN * DD) + d4;
    const float* __restrict__ Vb = V + (size_t)bt1 * (NN * DD) + d4;

    int beg  = offsets[n];
    int endo = offsets[n + 1];

    const float ninf = -__builtin_huge_valf();
    float4 accA = {ninf, ninf, ninf, ninf};
    float4 accB = {ninf, ninf, ninf, ninf};

    int j = beg;
    for (; j + 4 <= endo; j += 4) {
        int   s0 = esrc[j],   s1 = esrc[j+1], s2 = esrc[j+2], s3 = esrc[j+3];
        float w0 = ew[j],     w1 = ew[j+1],   w2 = ew[j+2],   w3 = ew[j+3];
        float4 a0 = *reinterpret_cast<const float4*>(Va + s0 * DD);
        float4 a1 = *reinterpret_cast<const float4*>(Va + s1 * DD);
        float4 a2 = *reinterpret_cast<const float4*>(Va + s2 * DD);
        float4 a3 = *reinterpret_cast<const float4*>(Va + s3 * DD);
        float4 b0 = *reinterpret_cast<const float4*>(Vb + s0 * DD);
        float4 b1 = *reinterpret_cast<const float4*>(Vb + s1 * DD);
        float4 b2 = *reinterpret_cast<const float4*>(Vb + s2 * DD);
        float4 b3 = *reinterpret_cast<const float4*>(Vb + s3 * DD);
        accA.x = fmaxf(accA.x, fmaxf(fmaxf(a0.x*w0, a1.x*w1), fmaxf(a2.x*w2, a3.x*w3)));
        accA.y = fmaxf(accA.y, fmaxf(fmaxf(a0.y*w0, a1.y*w1), fmaxf(a2.y*w2, a3.y*w3)));
        accA.z = fmaxf(accA.z, fmaxf(fmaxf(a0.z*w0, a1.z*w1), fmaxf(a2.z*w2, a3.z*w3)));
        accA.w = fmaxf(accA.w, fmaxf(fmaxf(a0.w*w0, a1.w*w1), fmaxf(a2.w*w2, a3.w*w3)));
        accB.x = fmaxf(accB.x, fmaxf(fmaxf(b0.x*w0, b1.x*w1), fmaxf(b2.x*w2, b3.x*w3)));
        accB.y = fmaxf(accB.y, fmaxf(fmaxf(b0.y*w0, b1.y*w1), fmaxf(b2.y*w2, b3.y*w3)));
        accB.z = fmaxf(accB.z, fmaxf(fmaxf(b0.z*w0, b1.z*w1), fmaxf(b2.z*w2, b3.z*w3)));
        accB.w = fmaxf(accB.w, fmaxf(fmaxf(b0.w*w0, b1.w*w1), fmaxf(b2.w*w2, b3.w*w3)));
    }
    if (!PADDED) {
        for (; j < endo; ++j) {
            int   s  = esrc[j];
            float we = ew[j];
            float4 a = *reinterpret_cast<const float4*>(Va + s * DD);
            float4 b = *reinterpret_cast<const float4*>(Vb + s * DD);
            accA.x = fmaxf(accA.x, a.x * we);
            accA.y = fmaxf(accA.y, a.y * we);
            accA.z = fmaxf(accA.z, a.z * we);
            accA.w = fmaxf(accA.w, a.w * we);
            accB.x = fmaxf(accB.x, b.x * we);
            accB.y = fmaxf(accB.y, b.y * we);
            accB.z = fmaxf(accB.z, b.z * we);
            accB.w = fmaxf(accB.w, b.w * we);
        }
    }

    float4 ra, rb;
    ra.x = (accA.x == ninf) ? 0.0f : accA.x;
    ra.y = (accA.y == ninf) ? 0.0f : accA.y;
    ra.z = (accA.z == ninf) ? 0.0f : accA.z;
    ra.w = (accA.w == ninf) ? 0.0f : accA.w;
    rb.x = (accB.x == ninf) ? 0.0f : accB.x;
    rb.y = (accB.y == ninf) ? 0.0f : accB.y;
    rb.z = (accB.z == ninf) ? 0.0f : accB.z;
    rb.w = (accB.w == ninf) ? 0.0f : accB.w;
    *reinterpret_cast<float4*>(out + ((size_t)bt0 * NN + n) * DD + d4) = ra;
    *reinterpret_cast<float4*>(out + ((size_t)bt1 * NN + n) * DD + d4) = rb;
}

// ---------------- launch ----------------

extern "C" void kernel_launch(void* const* d_in, const int* in_sizes, int n_in,
                              void* d_out, int out_size, void* d_ws, size_t ws_size,
                              hipStream_t stream) {
    const float* V   = (const float*)d_in[0];
    const int*   src = (const int*)d_in[1];
    const int*   dst = (const int*)d_in[2];
    const float* w   = (const float*)d_in[3];
    float* out = (float*)d_out;

    // ws layout (4B elems): counts[NN] | offsets[NN+1] | cursor[NN] | esrc[cap] | ew[cap]
    size_t need_pad = (size_t)(3 * NN + 1 + 2 * NEP) * 4;
    bool padded = ws_size >= need_pad;
    int cap = padded ? NEP : NE;

    int* ws_i = (int*)d_ws;
    int*   counts  = ws_i;
    int*   offsets = ws_i + NN;
    int*   cursor  = ws_i + 2 * NN + 1;
    int*   esrc    = ws_i + 3 * NN + 1;
    float* ew      = (float*)(ws_i + 3 * NN + 1 + cap);

    hipMemsetAsync(counts, 0, NN * sizeof(int), stream);
    k_hist<<<(NE + 255) / 256, 256, 0, stream>>>(dst, counts);
    k_scan<<<1, SCAN_THREADS, 0, stream>>>(counts, offsets, cursor, esrc, ew,
                                           padded ? 4 : 1);
    k_scatter<<<(NE + 255) / 256, 256, 0, stream>>>(src, dst, w, cursor, esrc, ew);

    int nblocks = NXCD * BTD_MAX * NCHUNK;   // 7536
    if (padded)
        k_main<true><<<nblocks, 256, 0, stream>>>(V, offsets, esrc, ew, out);
    else
        k_main<false><<<nblocks, 256, 0, stream>>>(V, offsets, esrc, ew, out);
}